// Round 11
// baseline (161.337 us; speedup 1.0000x reference)
//
#include <hip/hip_runtime.h>

#define BATCH 128

typedef float v2f __attribute__((ext_vector_type(2)));
typedef float v4f __attribute__((ext_vector_type(4)));

__device__ __constant__ float GC[16][4] = {
  {0,0,0,0},{0,0,0,1},{0,1,0,-1},{0,1,0,0},
  {0,0,1,-1},{0,0,1,0},{0,1,1,-2},{0,1,1,-1},
  {1,-1,-1,1},{1,-1,-1,2},{1,0,-1,0},{1,0,-1,1},
  {1,-1,0,0},{1,-1,0,1},{1,0,0,-1},{1,0,0,0}};

// ---- packed fp32 helpers (V_PK_FMA/MUL exist on gfx950; V_PK_MAX does NOT) ----
__device__ __forceinline__ v2f pk_mul(v2f a, v2f b) {
  v2f d;
  asm("v_pk_mul_f32 %0, %1, %2" : "=v"(d) : "v"(a), "v"(b));
  return d;
}
// r = w0 + w1*a + w2*b + w3*(a*b), per half; w01=(w0,w1) pair, w23=(w2,w3).
__device__ __forceinline__ v2f gate2pk(v2f a, v2f b, v2f w01, v2f w23) {
  v2f t = pk_mul(a, b);
  v2f d;
  asm("v_pk_fma_f32 %0, %1, %2, %2 op_sel:[0,1,0] op_sel_hi:[1,1,0]"
      : "=v"(d) : "v"(a), "v"(w01));
  asm("v_pk_fma_f32 %0, %1, %2, %0 op_sel:[0,0,0] op_sel_hi:[1,0,1]"
      : "+v"(d) : "v"(b), "v"(w23));
  asm("v_pk_fma_f32 %0, %1, %2, %0 op_sel:[0,1,0] op_sel_hi:[1,1,1]"
      : "+v"(d) : "v"(t), "v"(w23));
  return d;
}
__device__ __forceinline__ v4f gate4pk(v4f a, v4f b, v2f w01, v2f w23) {
  v4f r;
  r.xy = gate2pk(a.xy, b.xy, w01, w23);
  r.zw = gate2pk(a.zw, b.zw, w01, w23);
  return r;
}
__device__ __forceinline__ v4f max4(v4f a, v4f b) {
  v4f d;
  d.x = fmaxf(a.x, b.x); d.y = fmaxf(a.y, b.y);
  d.z = fmaxf(a.z, b.z); d.w = fmaxf(a.w, b.w);
  return d;
}

__device__ __forceinline__ void mix_one(const float* lp, float* op) {
  // logits are 0.01*N(0,1) (+5 on slot 3): exp() safe without max-shift
  float e[16];
  float s = 0.f;
  #pragma unroll
  for (int i = 0; i < 16; ++i) { e[i] = __expf(lp[i]); s += e[i]; }
  float inv = 1.0f / s;
  float w0 = 0.f, w1 = 0.f, w2 = 0.f, w3 = 0.f;
  #pragma unroll
  for (int i = 0; i < 16; ++i) {
    float p = e[i] * inv;
    w0 = fmaf(p, GC[i][0], w0);
    w1 = fmaf(p, GC[i][1], w1);
    w2 = fmaf(p, GC[i][2], w2);
    w3 = fmaf(p, GC[i][3], w3);
  }
  op[0] = w0; op[1] = w1; op[2] = w2; op[3] = w3;
}

struct PrepArgs {
  const float* x;
  const float* logits[7];
  float* outm[7];
  float* xtb;
  float* out;
};

// blocks 0..326: weight mix; 327..470: transpose+binarize x; 471: zero out
__global__ __launch_bounds__(256) void prep_k(PrepArgs A) {
  __shared__ float tile[64 * 129];
  int blk = blockIdx.x;
  if (blk < 327) {
    int gid = blk * 256 + threadIdx.x;
    const int n[7] = {224, 896, 3584, 7168, 40960, 20480, 10240};
    if (gid < 83552) {
      int g = gid, seg = 0;
      while (seg < 6 && g >= n[seg]) { g -= n[seg]; ++seg; }
      mix_one(A.logits[seg] + (size_t)g * 16, A.outm[seg] + (size_t)g * 4);
    }
  } else if (blk < 327 + 144) {
    int tb = blk - 327;
    int c    = tb / 16;             // binarized channel 0..8
    int pix0 = (tb % 16) * 64;
    int ti = c / 3, rgb = c - ti * 3;
    float th = 0.25f * (float)(ti + 1);
    {
      int pix = threadIdx.x & 63;
      int b0  = threadIdx.x >> 6;
      #pragma unroll 4
      for (int i = 0; i < 32; ++i) {
        int b = b0 + i * 4;
        float xv = A.x[(size_t)(b * 3 + rgb) * 1024 + pix0 + pix];
        tile[pix * 129 + b] = (xv > th) ? 1.f : 0.f;
      }
    }
    __syncthreads();
    {
      int b  = threadIdx.x & 127;
      int p0 = threadIdx.x >> 7;
      #pragma unroll 4
      for (int i = 0; i < 32; ++i) {
        int pix = p0 + i * 2;
        A.xtb[(size_t)(c * 1024 + pix0 + pix) * BATCH + b] = tile[pix * 129 + b];
      }
    }
  } else {
    int t = threadIdx.x;
    #pragma unroll
    for (int i = 0; i < 5; ++i) A.out[t * 5 + i] = 0.f;  // 1280 floats
  }
}

// Transposed tree-conv+pool, wide-load version.
// One output row per wave. Lane = (xi<<5)|bq: xi picks the x pool-position,
// bq the batch quad. Each (leaf,y) needs pixels x and x+1 (512 B apart in the
// transposed layout) -> ONE dwordx4 wave-load (1 KB) covers both: lanes 0-31
// get pixel x, lanes 32-63 pixel x+1. Halves conv VMEM instructions (32->16
// per row). Pool-max over x via shfl_xor(32); store from lanes 0-31.
// Row id wave-uniform -> leaf/weight s_loads; x-boundary cases are
// wave-uniform branches with a single-pixel fallback.
template <int H, int W>
__global__ __launch_bounds__(256) void conv_t(
    const float* __restrict__ in_t, const int* __restrict__ li_g,
    const float* __restrict__ m, float* __restrict__ out_t) {
  constexpr int PH = H / 2, PWD = W / 2, PIX = PH * PWD;
  int wave = threadIdx.x >> 6;
  int lane = threadIdx.x & 63;
  int xi   = lane >> 5;            // which x of the pool pair
  int q = __builtin_amdgcn_readfirstlane(blockIdx.x * 4 + wave);
  int o = q / PIX;
  int p = q - o * PIX;
  int ph = p / PWD;
  int pw = p - ph * PWD;

  const int* li = li_g + o * 8;
  const v4f* mv = (const v4f*)(m + o * 28);
  v4f g0 = mv[0], g1 = mv[1], g2 = mv[2], g3 = mv[3];
  v4f g4 = mv[4], g5 = mv[5], g6 = mv[6];

  v4f best = {-1e30f, -1e30f, -1e30f, -1e30f};
  #pragma unroll
  for (int half = 0; half < 2; ++half) {
    v4f v[8];
    #pragma unroll
    for (int l = 0; l < 8; ++l) {
      int idx = li[l];
      int c = idx / 9;
      int k = idx - c * 9;
      int di = k / 3 - 1;
      int dj = (k - (k / 3) * 3) - 1;
      const float* plane = in_t + (size_t)(c * H * W) * BATCH;
      int y  = 2 * ph + half + di;
      int xb = 2 * pw + dj;          // x of lanes 0-31; lanes 32-63 read xb+1
      v4f val = {0.f, 0.f, 0.f, 0.f};
      if ((unsigned)y < (unsigned)H) {        // uniform
        bool vlo = (xb >= 0);                 // uniform
        bool vhi = (xb + 1 < W);              // uniform
        int px0 = y * W + xb;
        if (vlo && vhi) {
          val = ((const v4f*)(plane + (size_t)px0 * BATCH))[lane];
        } else {
          int pv = vlo ? px0 : (px0 + 1);     // the single valid pixel
          v4f t = ((const v4f*)(plane + (size_t)pv * BATCH))[lane & 31];
          v4f z = {0.f, 0.f, 0.f, 0.f};
          val = (xi == (vlo ? 0 : 1)) ? t : z;
        }
      }
      v[l] = val;
    }
    v4f u0 = gate4pk(v[0], v[1], g0.xy, g0.zw);
    v4f u1 = gate4pk(v[2], v[3], g1.xy, g1.zw);
    v4f u2 = gate4pk(v[4], v[5], g2.xy, g2.zw);
    v4f u3 = gate4pk(v[6], v[7], g3.xy, g3.zw);
    v4f s0 = gate4pk(u0, u1, g4.xy, g4.zw);
    v4f s1 = gate4pk(u2, u3, g5.xy, g5.zw);
    v4f r  = gate4pk(s0, s1, g6.xy, g6.zw);
    best = max4(best, r);
  }
  // pool-max across the two x positions (lanes i <-> i^32)
  v4f other;
  other.x = __shfl_xor(best.x, 32, 64);
  other.y = __shfl_xor(best.y, 32, 64);
  other.z = __shfl_xor(best.z, 32, 64);
  other.w = __shfl_xor(best.w, 32, 64);
  best = max4(best, other);
  if (lane < 32)
    ((v4f*)(out_t + (size_t)q * BATCH))[lane] = best;
}

// Logic layer, transposed (D,B). 16 rows per block (4/wave, stride-4).
__global__ __launch_bounds__(256) void logic_k(
    const float* __restrict__ in, const int* __restrict__ aidx,
    const int* __restrict__ bidx, const float* __restrict__ m,
    float* __restrict__ out) {
  int wave = threadIdx.x >> 6;
  int b2   = threadIdx.x & 63;
  int j0 = blockIdx.x * 16 + wave;
  #pragma unroll
  for (int it = 0; it < 4; ++it) {
    int j = __builtin_amdgcn_readfirstlane(j0 + it * 4);
    int ai = aidx[j];
    int bi = bidx[j];
    v4f w = ((const v4f*)m)[j];
    v2f a = ((const v2f*)(in + (size_t)ai * BATCH))[b2];
    v2f b = ((const v2f*)(in + (size_t)bi * BATCH))[b2];
    ((v2f*)(out + (size_t)j * BATCH))[b2] = gate2pk(a, b, w.xy, w.zw);
  }
}

// Final logic layer fused with group-sum, reduction-hierarchy version:
// 40 blocks = 4 per class, 256 consecutive rows each. Per-wave register
// accumulation over 64 rows -> LDS cross-wave reduce -> 128 atomics per
// block (5120 total, ~4 per cell).
__global__ __launch_bounds__(256) void logic3_gsum_k(
    const float* __restrict__ in, const int* __restrict__ aidx,
    const int* __restrict__ bidx, const float* __restrict__ m,
    float* __restrict__ out) {
  __shared__ v2f red[4][64];
  int wave = threadIdx.x >> 6;
  int b2   = threadIdx.x & 63;
  int base = __builtin_amdgcn_readfirstlane(blockIdx.x * 256 + wave * 64);
  int cls  = base >> 10;
  v2f s = {0.f, 0.f};
  #pragma unroll 4
  for (int it = 0; it < 64; ++it) {
    int j = base + it;
    int ai = aidx[j];
    int bi = bidx[j];
    v4f w = ((const v4f*)m)[j];
    v2f a = ((const v2f*)(in + (size_t)ai * BATCH))[b2];
    v2f b = ((const v2f*)(in + (size_t)bi * BATCH))[b2];
    s += gate2pk(a, b, w.xy, w.zw);
  }
  red[wave][b2] = s;
  __syncthreads();
  if (threadIdx.x < 64) {
    v2f t = red[0][b2] + red[1][b2] + red[2][b2] + red[3][b2];
    atomicAdd(&out[(2 * b2) * 10 + cls], t.x * 0.01f);
    atomicAdd(&out[(2 * b2 + 1) * 10 + cls], t.y * 0.01f);
  }
}

extern "C" void kernel_launch(void* const* d_in, const int* in_sizes, int n_in,
                              void* d_out, int out_size, void* d_ws, size_t ws_size,
                              hipStream_t stream) {
  const float* x   = (const float*)d_in[0];
  const int*   c1i = (const int*)d_in[1];
  const float* c1w = (const float*)d_in[2];
  const int*   c2i = (const int*)d_in[3];
  const float* c2w = (const float*)d_in[4];
  const int*   c3i = (const int*)d_in[5];
  const float* c3w = (const float*)d_in[6];
  const int*   c4i = (const int*)d_in[7];
  const float* c4w = (const float*)d_in[8];
  const int*   l1a = (const int*)d_in[9];
  const int*   l1b = (const int*)d_in[10];
  const float* l1w = (const float*)d_in[11];
  const int*   l2a = (const int*)d_in[12];
  const int*   l2b = (const int*)d_in[13];
  const float* l2w = (const float*)d_in[14];
  const int*   l3a = (const int*)d_in[15];
  const int*   l3b = (const int*)d_in[16];
  const float* l3w = (const float*)d_in[17];

  float* ws = (float*)d_ws;
  float* mc1 = ws;              // 224*4
  float* mc2 = mc1 + 896;       // 896*4
  float* mc3 = mc2 + 3584;      // 3584*4
  float* mc4 = mc3 + 14336;     // 7168*4
  float* ml1 = mc4 + 28672;     // 40960*4
  float* ml2 = ml1 + 163840;    // 20480*4
  float* ml3 = ml2 + 81920;     // 10240*4
  float* xtb = ml3 + 40960;     // 9216*128 binarized, transposed
  float* h1  = xtb + 1179648;   // 8192*128
  float* h2  = h1 + 1048576;    // 8192*128
  float* h3  = h2 + 1048576;    // 8192*128
  float* h4  = h3 + 1048576;    // 4096*128
  float* g1  = h4 + 524288;     // 40960*128
  float* g2  = g1 + 5242880;    // 20480*128

  PrepArgs A;
  A.x = x;
  A.logits[0] = c1w; A.outm[0] = mc1;
  A.logits[1] = c2w; A.outm[1] = mc2;
  A.logits[2] = c3w; A.outm[2] = mc3;
  A.logits[3] = c4w; A.outm[3] = mc4;
  A.logits[4] = l1w; A.outm[4] = ml1;
  A.logits[5] = l2w; A.outm[5] = ml2;
  A.logits[6] = l3w; A.outm[6] = ml3;
  A.xtb = xtb;
  A.out = (float*)d_out;
  prep_k<<<472, 256, 0, stream>>>(A);

  conv_t<32, 32><<<8192 / 4, 256, 0, stream>>>(xtb, c1i, mc1, h1);
  conv_t<16, 16><<<8192 / 4, 256, 0, stream>>>(h1, c2i, mc2, h2);
  conv_t<8, 8><<<8192 / 4, 256, 0, stream>>>(h2, c3i, mc3, h3);
  conv_t<4, 4><<<4096 / 4, 256, 0, stream>>>(h3, c4i, mc4, h4);

  logic_k<<<40960 / 16, 256, 0, stream>>>(h4, l1a, l1b, ml1, g1);
  logic_k<<<20480 / 16, 256, 0, stream>>>(g1, l2a, l2b, ml2, g2);
  logic3_gsum_k<<<40, 256, 0, stream>>>(g2, l3a, l3b, ml3, (float*)d_out);
}

// Round 12
// 157.697 us; speedup vs baseline: 1.0231x; 1.0231x over previous
//
#include <hip/hip_runtime.h>

#define BATCH 128

typedef float v2f __attribute__((ext_vector_type(2)));
typedef float v4f __attribute__((ext_vector_type(4)));

__device__ __constant__ float GC[16][4] = {
  {0,0,0,0},{0,0,0,1},{0,1,0,-1},{0,1,0,0},
  {0,0,1,-1},{0,0,1,0},{0,1,1,-2},{0,1,1,-1},
  {1,-1,-1,1},{1,-1,-1,2},{1,0,-1,0},{1,0,-1,1},
  {1,-1,0,0},{1,-1,0,1},{1,0,0,-1},{1,0,0,0}};

// ---- packed fp32 helpers (V_PK_FMA/MUL exist on gfx950; V_PK_MAX does NOT) ----
__device__ __forceinline__ v2f pk_mul(v2f a, v2f b) {
  v2f d;
  asm("v_pk_mul_f32 %0, %1, %2" : "=v"(d) : "v"(a), "v"(b));
  return d;
}
__device__ __forceinline__ v2f max2(v2f a, v2f b) {
  v2f d;
  d.x = fmaxf(a.x, b.x);
  d.y = fmaxf(a.y, b.y);
  return d;
}
// r = w0 + w1*a + w2*b + w3*(a*b), per half; w01=(w0,w1) pair, w23=(w2,w3).
__device__ __forceinline__ v2f gate2pk(v2f a, v2f b, v2f w01, v2f w23) {
  v2f t = pk_mul(a, b);
  v2f d;
  asm("v_pk_fma_f32 %0, %1, %2, %2 op_sel:[0,1,0] op_sel_hi:[1,1,0]"
      : "=v"(d) : "v"(a), "v"(w01));
  asm("v_pk_fma_f32 %0, %1, %2, %0 op_sel:[0,0,0] op_sel_hi:[1,0,1]"
      : "+v"(d) : "v"(b), "v"(w23));
  asm("v_pk_fma_f32 %0, %1, %2, %0 op_sel:[0,1,0] op_sel_hi:[1,1,1]"
      : "+v"(d) : "v"(t), "v"(w23));
  return d;
}

__device__ __forceinline__ void mix_one(const float* lp, float* op) {
  // logits are 0.01*N(0,1) (+5 on slot 3): exp() safe without max-shift
  float e[16];
  float s = 0.f;
  #pragma unroll
  for (int i = 0; i < 16; ++i) { e[i] = __expf(lp[i]); s += e[i]; }
  float inv = 1.0f / s;
  float w0 = 0.f, w1 = 0.f, w2 = 0.f, w3 = 0.f;
  #pragma unroll
  for (int i = 0; i < 16; ++i) {
    float p = e[i] * inv;
    w0 = fmaf(p, GC[i][0], w0);
    w1 = fmaf(p, GC[i][1], w1);
    w2 = fmaf(p, GC[i][2], w2);
    w3 = fmaf(p, GC[i][3], w3);
  }
  op[0] = w0; op[1] = w1; op[2] = w2; op[3] = w3;
}

struct PrepArgs {
  const float* x;
  const float* logits[7];
  float* outm[7];
  float* xtb;
  float* out;
};

// blocks 0..326: weight mix; 327..470: transpose+binarize x; 471: zero out
__global__ __launch_bounds__(256) void prep_k(PrepArgs A) {
  __shared__ float tile[64 * 129];
  int blk = blockIdx.x;
  if (blk < 327) {
    int gid = blk * 256 + threadIdx.x;
    const int n[7] = {224, 896, 3584, 7168, 40960, 20480, 10240};
    if (gid < 83552) {
      int g = gid, seg = 0;
      while (seg < 6 && g >= n[seg]) { g -= n[seg]; ++seg; }
      mix_one(A.logits[seg] + (size_t)g * 16, A.outm[seg] + (size_t)g * 4);
    }
  } else if (blk < 327 + 144) {
    int tb = blk - 327;
    int c    = tb / 16;             // binarized channel 0..8
    int pix0 = (tb % 16) * 64;
    int ti = c / 3, rgb = c - ti * 3;
    float th = 0.25f * (float)(ti + 1);
    {
      int pix = threadIdx.x & 63;
      int b0  = threadIdx.x >> 6;
      #pragma unroll 4
      for (int i = 0; i < 32; ++i) {
        int b = b0 + i * 4;
        float xv = A.x[(size_t)(b * 3 + rgb) * 1024 + pix0 + pix];
        tile[pix * 129 + b] = (xv > th) ? 1.f : 0.f;
      }
    }
    __syncthreads();
    {
      int b  = threadIdx.x & 127;
      int p0 = threadIdx.x >> 7;
      #pragma unroll 4
      for (int i = 0; i < 32; ++i) {
        int pix = p0 + i * 2;
        A.xtb[(size_t)(c * 1024 + pix0 + pix) * BATCH + b] = tile[pix * 129 + b];
      }
    }
  } else {
    int t = threadIdx.x;
    #pragma unroll
    for (int i = 0; i < 5; ++i) A.out[t * 5 + i] = 0.f;  // 1280 floats
  }
}

// Transposed tree-conv+pool. One output row per wave (64 lanes x v2f = 128 batch).
// Row id is wave-uniform (readfirstlane) -> leaf/weight loads are s_load,
// boundary checks are uniform SALU branches.
template <int H, int W>
__global__ __launch_bounds__(256) void conv_t(
    const float* __restrict__ in_t, const int* __restrict__ li_g,
    const float* __restrict__ m, float* __restrict__ out_t) {
  constexpr int PH = H / 2, PWD = W / 2, PIX = PH * PWD;
  int wave = threadIdx.x >> 6;
  int b2   = threadIdx.x & 63;
  int q = __builtin_amdgcn_readfirstlane(blockIdx.x * 4 + wave);
  int o = q / PIX;
  int p = q - o * PIX;
  int ph = p / PWD;
  int pw = p - ph * PWD;

  const int* li = li_g + o * 8;
  const v4f* mv = (const v4f*)(m + o * 28);
  v4f g0 = mv[0], g1 = mv[1], g2 = mv[2], g3 = mv[3];
  v4f g4 = mv[4], g5 = mv[5], g6 = mv[6];

  v2f best = {-1e30f, -1e30f};
  #pragma unroll
  for (int half = 0; half < 2; ++half) {
    v2f v[2][8];
    #pragma unroll
    for (int l = 0; l < 8; ++l) {
      int idx = li[l];
      int c = idx / 9;
      int k = idx - c * 9;
      int di = k / 3 - 1;
      int dj = (k - (k / 3) * 3) - 1;
      const float* base = in_t + (size_t)(c * H * W) * BATCH;
      int y = 2 * ph + half + di;
      #pragma unroll
      for (int pi = 0; pi < 2; ++pi) {
        int x = 2 * pw + pi + dj;
        v2f val = {0.f, 0.f};
        if ((unsigned)y < (unsigned)H && (unsigned)x < (unsigned)W)
          val = ((const v2f*)(base + (size_t)(y * W + x) * BATCH))[b2];
        v[pi][l] = val;
      }
    }
    #pragma unroll
    for (int pi = 0; pi < 2; ++pi) {
      v2f u0 = gate2pk(v[pi][0], v[pi][1], g0.xy, g0.zw);
      v2f u1 = gate2pk(v[pi][2], v[pi][3], g1.xy, g1.zw);
      v2f u2 = gate2pk(v[pi][4], v[pi][5], g2.xy, g2.zw);
      v2f u3 = gate2pk(v[pi][6], v[pi][7], g3.xy, g3.zw);
      v2f s0 = gate2pk(u0, u1, g4.xy, g4.zw);
      v2f s1 = gate2pk(u2, u3, g5.xy, g5.zw);
      v2f r  = gate2pk(s0, s1, g6.xy, g6.zw);
      best = max2(best, r);
    }
  }
  ((v2f*)(out_t + (size_t)q * BATCH))[b2] = best;
}

// Logic layer, transposed (D,B). 16 rows per block (4/wave, stride-4).
__global__ __launch_bounds__(256) void logic_k(
    const float* __restrict__ in, const int* __restrict__ aidx,
    const int* __restrict__ bidx, const float* __restrict__ m,
    float* __restrict__ out) {
  int wave = threadIdx.x >> 6;
  int b2   = threadIdx.x & 63;
  int j0 = blockIdx.x * 16 + wave;
  #pragma unroll
  for (int it = 0; it < 4; ++it) {
    int j = __builtin_amdgcn_readfirstlane(j0 + it * 4);
    int ai = aidx[j];
    int bi = bidx[j];
    v4f w = ((const v4f*)m)[j];
    v2f a = ((const v2f*)(in + (size_t)ai * BATCH))[b2];
    v2f b = ((const v2f*)(in + (size_t)bi * BATCH))[b2];
    ((v2f*)(out + (size_t)j * BATCH))[b2] = gate2pk(a, b, w.xy, w.zw);
  }
}

// Final logic layer fused with group-sum, reduction-hierarchy version:
// 40 blocks = 4 per class, 256 consecutive rows each (256 | 1024 so a block
// never straddles a class). Per-wave register accumulation over 64 rows ->
// LDS cross-wave reduce -> 128 atomics per block (5120 total, ~4 per cell).
__global__ __launch_bounds__(256) void logic3_gsum_k(
    const float* __restrict__ in, const int* __restrict__ aidx,
    const int* __restrict__ bidx, const float* __restrict__ m,
    float* __restrict__ out) {
  __shared__ v2f red[4][64];
  int wave = threadIdx.x >> 6;
  int b2   = threadIdx.x & 63;
  int base = __builtin_amdgcn_readfirstlane(blockIdx.x * 256 + wave * 64);
  int cls  = base >> 10;
  v2f s = {0.f, 0.f};
  #pragma unroll 4
  for (int it = 0; it < 64; ++it) {
    int j = base + it;
    int ai = aidx[j];
    int bi = bidx[j];
    v4f w = ((const v4f*)m)[j];
    v2f a = ((const v2f*)(in + (size_t)ai * BATCH))[b2];
    v2f b = ((const v2f*)(in + (size_t)bi * BATCH))[b2];
    s += gate2pk(a, b, w.xy, w.zw);
  }
  red[wave][b2] = s;
  __syncthreads();
  if (threadIdx.x < 64) {
    v2f t = red[0][b2] + red[1][b2] + red[2][b2] + red[3][b2];
    atomicAdd(&out[(2 * b2) * 10 + cls], t.x * 0.01f);
    atomicAdd(&out[(2 * b2 + 1) * 10 + cls], t.y * 0.01f);
  }
}

extern "C" void kernel_launch(void* const* d_in, const int* in_sizes, int n_in,
                              void* d_out, int out_size, void* d_ws, size_t ws_size,
                              hipStream_t stream) {
  const float* x   = (const float*)d_in[0];
  const int*   c1i = (const int*)d_in[1];
  const float* c1w = (const float*)d_in[2];
  const int*   c2i = (const int*)d_in[3];
  const float* c2w = (const float*)d_in[4];
  const int*   c3i = (const int*)d_in[5];
  const float* c3w = (const float*)d_in[6];
  const int*   c4i = (const int*)d_in[7];
  const float* c4w = (const float*)d_in[8];
  const int*   l1a = (const int*)d_in[9];
  const int*   l1b = (const int*)d_in[10];
  const float* l1w = (const float*)d_in[11];
  const int*   l2a = (const int*)d_in[12];
  const int*   l2b = (const int*)d_in[13];
  const float* l2w = (const float*)d_in[14];
  const int*   l3a = (const int*)d_in[15];
  const int*   l3b = (const int*)d_in[16];
  const float* l3w = (const float*)d_in[17];

  float* ws = (float*)d_ws;
  float* mc1 = ws;              // 224*4
  float* mc2 = mc1 + 896;       // 896*4
  float* mc3 = mc2 + 3584;      // 3584*4
  float* mc4 = mc3 + 14336;     // 7168*4
  float* ml1 = mc4 + 28672;     // 40960*4
  float* ml2 = ml1 + 163840;    // 20480*4
  float* ml3 = ml2 + 81920;     // 10240*4
  float* xtb = ml3 + 40960;     // 9216*128 binarized, transposed
  float* h1  = xtb + 1179648;   // 8192*128
  float* h2  = h1 + 1048576;    // 8192*128
  float* h3  = h2 + 1048576;    // 8192*128
  float* h4  = h3 + 1048576;    // 4096*128
  float* g1  = h4 + 524288;     // 40960*128
  float* g2  = g1 + 5242880;    // 20480*128

  PrepArgs A;
  A.x = x;
  A.logits[0] = c1w; A.outm[0] = mc1;
  A.logits[1] = c2w; A.outm[1] = mc2;
  A.logits[2] = c3w; A.outm[2] = mc3;
  A.logits[3] = c4w; A.outm[3] = mc4;
  A.logits[4] = l1w; A.outm[4] = ml1;
  A.logits[5] = l2w; A.outm[5] = ml2;
  A.logits[6] = l3w; A.outm[6] = ml3;
  A.xtb = xtb;
  A.out = (float*)d_out;
  prep_k<<<472, 256, 0, stream>>>(A);

  conv_t<32, 32><<<8192 / 4, 256, 0, stream>>>(xtb, c1i, mc1, h1);
  conv_t<16, 16><<<8192 / 4, 256, 0, stream>>>(h1, c2i, mc2, h2);
  conv_t<8, 8><<<8192 / 4, 256, 0, stream>>>(h2, c3i, mc3, h3);
  conv_t<4, 4><<<4096 / 4, 256, 0, stream>>>(h3, c4i, mc4, h4);

  logic_k<<<40960 / 16, 256, 0, stream>>>(h4, l1a, l1b, ml1, g1);
  logic_k<<<20480 / 16, 256, 0, stream>>>(g1, l2a, l2b, ml2, g2);
  logic3_gsum_k<<<40, 256, 0, stream>>>(g2, l3a, l3b, ml3, (float*)d_out);
}